// Round 1
// baseline (194.259 us; speedup 1.0000x reference)
//
#include <hip/hip_runtime.h>

#define IMG 512
#define CS 36                     // shorts per Ht column: 2 ring slots (32) + 4 pad
#define CH_STRIDE (16 * CS)       // 576 shorts: one channel (16 cols) of one wave
#define WV_STRIDE (5 * CH_STRIDE) // 2880 shorts: one wave's 5 channels

typedef short short8  __attribute__((ext_vector_type(8)));
typedef float floatx4 __attribute__((ext_vector_type(4)));
typedef int   intx2   __attribute__((ext_vector_type(2)));

// 1D Gaussian (sigma=1.5, K=11) — identical values to prior rounds.
__device__ static constexpr float W11F[11] = {
    0.00102838f, 0.00759876f, 0.03600077f, 0.10936069f, 0.21300554f,
    0.26601173f,
    0.21300554f, 0.10936069f, 0.03600077f, 0.00759876f, 0.00102838f};

// pack two fp32 -> two bf16 (round-half-up; finite positive values)
__device__ __forceinline__ unsigned pack2bf16(float a, float b) {
    const unsigned ua = __float_as_uint(a) + 0x8000u;
    const unsigned ub = __float_as_uint(b) + 0x8000u;
    return __builtin_amdgcn_perm(ub, ua, 0x07060302u);
}

__device__ __forceinline__ void ht_store(ushort* p, floatx4 c) {
    intx2 d;
    d.x = (int)pack2bf16(c[0], c[1]);
    d.y = (int)pack2bf16(c[2], c[3]);
    *(intx2*)p = d;               // 8-B aligned by construction
}

__device__ __forceinline__ short8 ht_load(const ushort* p) {
    union { intx2 d[2]; short8 s; } u;
    u.d[0] = *(const intx2*)p;
    u.d[1] = *(const intx2*)(p + 4);
    return u.s;
}

// Block = 2 waves (128 thr). Wave = 16 out-cols x 64 out-rows: 5 staged
// 16-row tiles feed 4 output windows through a 2-slot LDS ring (tile t ->
// slot t&1). Three register buffer sets (A,B,C) rotate so every global
// staging load issues 3-5 macro-stages before its consuming COMPT.
// Straight-line schedule, named register buffers only (no spillable arrays).
__global__ __launch_bounds__(128, 6) void ssim_mfma_ring2(
        const float* __restrict__ pred, const float* __restrict__ gt,
        float* __restrict__ partials)
{
    __shared__ ushort Ht[2 * WV_STRIDE];   // 11,520 B -> 13 blocks/CU
    __shared__ ushort wlut[16];
    __shared__ float wsum[2];

    const int tid  = threadIdx.x;
    const int wv   = tid >> 6;
    const int lane = tid & 63;
    const int n    = lane & 15;
    const int quad = lane >> 4;

    if (tid < 16) {
        const float w = (tid < 11) ? W11F[tid] : 0.f;
        wlut[tid] = (ushort)((__float_as_uint(w) + 0x8000u) >> 16);
    }
    __syncthreads();

    // band fragment: w[(quad*8+j) - n - 3]; B in H-pass, A in V-pass.
    short8 band;
#pragma unroll
    for (int j = 0; j < 8; ++j) {
        const int t = quad * 8 + j - n - 3;
        band[j] = (short)wlut[((unsigned)t < 11u) ? t : 15];
    }

    const int bx = blockIdx.x, by = blockIdx.y, plane = blockIdx.z;
    const long pb = (long)plane * (IMG * IMG);
    const float* pplane = pred + pb;
    const float* gplane = gt + pb;
    const int xs  = bx * 32 + wv * 16 - 8;  // 32-col input window start
    const int y0  = by * 64;                // 64-row output strip
    ushort* ht    = &Ht[wv * WV_STRIDE];
    const bool cols_ok = (xs >= 0) && (xs + 32 <= IMG);

// stage tile t (16 input rows starting at y0-8+16t) into named buffers
#define LOADT(t, pf, gf)                                                     \
    {                                                                        \
        const int ys  = y0 - 8 + (t) * 16;                                   \
        const int row = ys + n;                                              \
        const int c0  = xs + quad * 8;                                       \
        if (cols_ok && ys >= 0 && ys + 16 <= IMG) {                          \
            const float* pr = pplane + (long)row * IMG + c0;                 \
            const float* gr = gplane + (long)row * IMG + c0;                 \
            *(float4*)&pf[0] = *(const float4*)pr;                           \
            *(float4*)&pf[4] = *(const float4*)(pr + 4);                     \
            *(float4*)&gf[0] = *(const float4*)gr;                           \
            *(float4*)&gf[4] = *(const float4*)(gr + 4);                     \
        } else {                                                             \
            const bool rv = (unsigned)row < (unsigned)IMG;                   \
            const int rowc = rv ? row : 0;                                   \
            const float* pr = pplane + (long)rowc * IMG;                     \
            const float* gr = gplane + (long)rowc * IMG;                     \
            _Pragma("unroll")                                                \
            for (int j = 0; j < 8; ++j) {                                    \
                const int cc = c0 + j;                                       \
                const bool ok = rv && ((unsigned)cc < (unsigned)IMG);        \
                const int ccc = ok ? cc : 0;                                 \
                const float pv = pr[ccc], gv = gr[ccc];                      \
                pf[j] = ok ? pv : 0.f;                                       \
                gf[j] = ok ? gv : 0.f;                                       \
            }                                                                \
        }                                                                    \
    }

// H-conv tile t via 5 MFMAs, store into ring slot t&1 (k = slot*16 + m)
#define COMPT(t, pf, gf)                                                     \
    {                                                                        \
        union { unsigned u[4]; short8 s; } ap, ag, app, agg, apg;            \
        _Pragma("unroll")                                                    \
        for (int h = 0; h < 4; ++h) {                                        \
            const float p0 = pf[2*h], p1 = pf[2*h+1];                        \
            const float g0 = gf[2*h], g1 = gf[2*h+1];                        \
            ap.u [h] = pack2bf16(p0, p1);                                    \
            ag.u [h] = pack2bf16(g0, g1);                                    \
            app.u[h] = pack2bf16(p0 * p0, p1 * p1);                          \
            agg.u[h] = pack2bf16(g0 * g0, g1 * g1);                          \
            apg.u[h] = pack2bf16(p0 * g0, p1 * g1);                          \
        }                                                                    \
        const floatx4 z = {0.f, 0.f, 0.f, 0.f};                              \
        const floatx4 cp  = __builtin_amdgcn_mfma_f32_16x16x32_bf16(ap.s,  band, z, 0, 0, 0); \
        const floatx4 cg  = __builtin_amdgcn_mfma_f32_16x16x32_bf16(ag.s,  band, z, 0, 0, 0); \
        const floatx4 cpp = __builtin_amdgcn_mfma_f32_16x16x32_bf16(app.s, band, z, 0, 0, 0); \
        const floatx4 cgg = __builtin_amdgcn_mfma_f32_16x16x32_bf16(agg.s, band, z, 0, 0, 0); \
        const floatx4 cpg = __builtin_amdgcn_mfma_f32_16x16x32_bf16(apg.s, band, z, 0, 0, 0); \
        const int wb = n * CS + ((t) & 1) * 16 + quad * 4;                   \
        ht_store(&ht[0 * CH_STRIDE + wb], cp);                               \
        ht_store(&ht[1 * CH_STRIDE + wb], cg);                               \
        ht_store(&ht[2 * CH_STRIDE + wb], cpp);                              \
        ht_store(&ht[3 * CH_STRIDE + wb], cgg);                              \
        ht_store(&ht[4 * CH_STRIDE + wb], cpg);                              \
    }

// V window w: lower 16 k-rows from ring slot SLO, upper from slot SHI
#define VPASS(SLO, SHI)                                                      \
    {                                                                        \
        const int koff = ((quad < 2) ? (SLO) : (SHI)) * 16 + (quad & 1) * 8; \
        const int rb   = n * CS + koff;                                      \
        const short8 bp  = ht_load(&ht[0 * CH_STRIDE + rb]);                 \
        const short8 bg  = ht_load(&ht[1 * CH_STRIDE + rb]);                 \
        const short8 bpp = ht_load(&ht[2 * CH_STRIDE + rb]);                 \
        const short8 bgg = ht_load(&ht[3 * CH_STRIDE + rb]);                 \
        const short8 bpg = ht_load(&ht[4 * CH_STRIDE + rb]);                 \
        const floatx4 z = {0.f, 0.f, 0.f, 0.f};                              \
        const floatx4 mp  = __builtin_amdgcn_mfma_f32_16x16x32_bf16(band, bp,  z, 0, 0, 0); \
        const floatx4 mg  = __builtin_amdgcn_mfma_f32_16x16x32_bf16(band, bg,  z, 0, 0, 0); \
        const floatx4 mpp = __builtin_amdgcn_mfma_f32_16x16x32_bf16(band, bpp, z, 0, 0, 0); \
        const floatx4 mgg = __builtin_amdgcn_mfma_f32_16x16x32_bf16(band, bgg, z, 0, 0, 0); \
        const floatx4 mpg = __builtin_amdgcn_mfma_f32_16x16x32_bf16(band, bpg, z, 0, 0, 0); \
        _Pragma("unroll")                                                    \
        for (int r = 0; r < 4; ++r) {                                        \
            const float mu1 = mp[r], mu2 = mg[r];                            \
            const float mu1sq = mu1 * mu1, mu2sq = mu2 * mu2;                \
            const float mu12 = mu1 * mu2;                                    \
            const float s1  = mpp[r] - mu1sq;                                \
            const float s2  = mgg[r] - mu2sq;                                \
            const float s12 = mpg[r] - mu12;                                 \
            const float num = (2.f * mu12 + C1) * (2.f * s12 + C2);          \
            const float den = (mu1sq + mu2sq + C1) * (s1 + s2 + C2);         \
            lsum += num * __builtin_amdgcn_rcpf(den);                        \
        }                                                                    \
    }

    const float C1 = 1e-4f, C2 = 9e-4f;
    float lsum = 0.f;

    // named buffers, constant indices only -> stays in VGPRs
    float pA[8], gA[8], pB[8], gB[8], pC[8], gC[8];

    LOADT(0, pA, gA)
    LOADT(1, pB, gB)
    LOADT(2, pC, gC)
    COMPT(0, pA, gA)          // slot 0
    LOADT(3, pA, gA)
    COMPT(1, pB, gB)          // slot 1
    VPASS(0, 1)               // window 0: tiles 0,1
    LOADT(4, pB, gB)
    COMPT(2, pC, gC)          // slot 0
    VPASS(1, 0)               // window 1: tiles 1,2
    COMPT(3, pA, gA)          // slot 1
    VPASS(0, 1)               // window 2: tiles 2,3
    COMPT(4, pB, gB)          // slot 0
    VPASS(1, 0)               // window 3: tiles 3,4

    // ---- block reduction -> one partial per block ----
#pragma unroll
    for (int off = 32; off > 0; off >>= 1)
        lsum += __shfl_down(lsum, off);
    if (lane == 0) wsum[wv] = lsum;
    __syncthreads();
    if (tid == 0)
        partials[(plane * 8 + by) * 16 + bx] = wsum[0] + wsum[1];
}

__global__ __launch_bounds__(1024) void ssim_finalize(
        const float* __restrict__ partials, float* __restrict__ out,
        int nparts, double inv_n)
{
    __shared__ double ws[16];
    double s = 0.0;
    for (int i = threadIdx.x; i < nparts; i += 1024)
        s += (double)partials[i];
#pragma unroll
    for (int off = 32; off > 0; off >>= 1)
        s += __shfl_down(s, off);
    if ((threadIdx.x & 63) == 0) ws[threadIdx.x >> 6] = s;
    __syncthreads();
    if (threadIdx.x == 0) {
        double t = 0.0;
#pragma unroll
        for (int i = 0; i < 16; ++i) t += ws[i];
        out[0] = (float)(1.0 - t * inv_n);
    }
}

extern "C" void kernel_launch(void* const* d_in, const int* in_sizes, int n_in,
                              void* d_out, int out_size, void* d_ws, size_t ws_size,
                              hipStream_t stream)
{
    const float* pred = (const float*)d_in[0];
    const float* gt   = (const float*)d_in[1];
    float* out        = (float*)d_out;
    float* partials   = (float*)d_ws;          // 16*8*48 = 6144 floats

    const long n = (long)in_sizes[0];
    const int planes = (int)(n / (long)(IMG * IMG));   // B*C = 48

    dim3 grid(16, 8, planes);                  // 32-col x 64-row strips
    ssim_mfma_ring2<<<grid, 128, 0, stream>>>(pred, gt, partials);
    ssim_finalize<<<1, 1024, 0, stream>>>(partials, out,
                                          16 * 8 * planes, 1.0 / (double)n);
}

// Round 2
// 160.975 us; speedup vs baseline: 1.2068x; 1.2068x over previous
//
#include <hip/hip_runtime.h>

#define IMG 512
#define CS 36                     // shorts per Ht column: 2 ring slots (32) + 4 pad
#define CH_STRIDE (16 * CS)       // 576 shorts: one channel (16 cols) of one wave
#define WV_STRIDE (5 * CH_STRIDE) // 2880 shorts: one wave's 5 channels

typedef short short8  __attribute__((ext_vector_type(8)));
typedef float floatx4 __attribute__((ext_vector_type(4)));
typedef int   intx2   __attribute__((ext_vector_type(2)));

// 1D Gaussian (sigma=1.5, K=11) — identical values to prior rounds.
__device__ static constexpr float W11F[11] = {
    0.00102838f, 0.00759876f, 0.03600077f, 0.10936069f, 0.21300554f,
    0.26601173f,
    0.21300554f, 0.10936069f, 0.03600077f, 0.00759876f, 0.00102838f};

// pack two fp32 -> two bf16 (round-half-up; finite positive values)
__device__ __forceinline__ unsigned pack2bf16(float a, float b) {
    const unsigned ua = __float_as_uint(a) + 0x8000u;
    const unsigned ub = __float_as_uint(b) + 0x8000u;
    return __builtin_amdgcn_perm(ub, ua, 0x07060302u);
}

__device__ __forceinline__ void ht_store(ushort* p, floatx4 c) {
    intx2 d;
    d.x = (int)pack2bf16(c[0], c[1]);
    d.y = (int)pack2bf16(c[2], c[3]);
    *(intx2*)p = d;               // 8-B aligned by construction
}

__device__ __forceinline__ short8 ht_load(const ushort* p) {
    union { intx2 d[2]; short8 s; } u;
    u.d[0] = *(const intx2*)p;
    u.d[1] = *(const intx2*)(p + 4);
    return u.s;
}

// Block = 4 waves (256 thr), 64 out-cols per block for L2 halo sharing.
// Wave = 16 out-cols x 64 out-rows: 5 staged 16-row tiles feed 4 output
// windows through a 2-slot LDS ring (tile t -> slot t&1). THREE register
// buffer sets (A,B,C) rotate: every staging load issues 3 macro-stages
// before its consuming COMPT. No register cap beyond (256,4) -> cap 128,
// expected use ~64, NO spills (round-1 lesson: forcing 85 spilled).
__global__ __launch_bounds__(256, 4) void ssim_mfma_ring2(
        const float* __restrict__ pred, const float* __restrict__ gt,
        float* __restrict__ partials)
{
    __shared__ ushort Ht[4 * WV_STRIDE];   // 23,040 B
    __shared__ ushort wlut[16];
    __shared__ float wsum[4];

    const int tid  = threadIdx.x;
    const int wv   = tid >> 6;
    const int lane = tid & 63;
    const int n    = lane & 15;
    const int quad = lane >> 4;

    if (tid < 16) {
        const float w = (tid < 11) ? W11F[tid] : 0.f;
        wlut[tid] = (ushort)((__float_as_uint(w) + 0x8000u) >> 16);
    }
    __syncthreads();

    // band fragment: w[(quad*8+j) - n - 3]; B in H-pass, A in V-pass.
    short8 band;
#pragma unroll
    for (int j = 0; j < 8; ++j) {
        const int t = quad * 8 + j - n - 3;
        band[j] = (short)wlut[((unsigned)t < 11u) ? t : 15];
    }

    const int bx = blockIdx.x, by = blockIdx.y, plane = blockIdx.z;
    const long pb = (long)plane * (IMG * IMG);
    const float* pplane = pred + pb;
    const float* gplane = gt + pb;
    const int xs  = bx * 64 + wv * 16 - 8;  // 32-col input window start
    const int y0  = by * 64;                // 64-row output strip
    ushort* ht    = &Ht[wv * WV_STRIDE];
    const bool cols_ok = (xs >= 0) && (xs + 32 <= IMG);

// stage tile t (16 input rows starting at y0-8+16t) into named buffers
#define LOADT(t, pf, gf)                                                     \
    {                                                                        \
        const int ys  = y0 - 8 + (t) * 16;                                   \
        const int row = ys + n;                                              \
        const int c0  = xs + quad * 8;                                       \
        if (cols_ok && ys >= 0 && ys + 16 <= IMG) {                          \
            const float* pr = pplane + (long)row * IMG + c0;                 \
            const float* gr = gplane + (long)row * IMG + c0;                 \
            *(float4*)&pf[0] = *(const float4*)pr;                           \
            *(float4*)&pf[4] = *(const float4*)(pr + 4);                     \
            *(float4*)&gf[0] = *(const float4*)gr;                           \
            *(float4*)&gf[4] = *(const float4*)(gr + 4);                     \
        } else {                                                             \
            const bool rv = (unsigned)row < (unsigned)IMG;                   \
            const int rowc = rv ? row : 0;                                   \
            const float* pr = pplane + (long)rowc * IMG;                     \
            const float* gr = gplane + (long)rowc * IMG;                     \
            _Pragma("unroll")                                                \
            for (int j = 0; j < 8; ++j) {                                    \
                const int cc = c0 + j;                                       \
                const bool ok = rv && ((unsigned)cc < (unsigned)IMG);        \
                const int ccc = ok ? cc : 0;                                 \
                const float pv = pr[ccc], gv = gr[ccc];                      \
                pf[j] = ok ? pv : 0.f;                                       \
                gf[j] = ok ? gv : 0.f;                                       \
            }                                                                \
        }                                                                    \
    }

// H-conv tile t via 5 MFMAs, store into ring slot t&1 (k = slot*16 + m)
#define COMPT(t, pf, gf)                                                     \
    {                                                                        \
        union { unsigned u[4]; short8 s; } ap, ag, app, agg, apg;            \
        _Pragma("unroll")                                                    \
        for (int h = 0; h < 4; ++h) {                                        \
            const float p0 = pf[2*h], p1 = pf[2*h+1];                        \
            const float g0 = gf[2*h], g1 = gf[2*h+1];                        \
            ap.u [h] = pack2bf16(p0, p1);                                    \
            ag.u [h] = pack2bf16(g0, g1);                                    \
            app.u[h] = pack2bf16(p0 * p0, p1 * p1);                          \
            agg.u[h] = pack2bf16(g0 * g0, g1 * g1);                          \
            apg.u[h] = pack2bf16(p0 * g0, p1 * g1);                          \
        }                                                                    \
        const floatx4 z = {0.f, 0.f, 0.f, 0.f};                              \
        const floatx4 cp  = __builtin_amdgcn_mfma_f32_16x16x32_bf16(ap.s,  band, z, 0, 0, 0); \
        const floatx4 cg  = __builtin_amdgcn_mfma_f32_16x16x32_bf16(ag.s,  band, z, 0, 0, 0); \
        const floatx4 cpp = __builtin_amdgcn_mfma_f32_16x16x32_bf16(app.s, band, z, 0, 0, 0); \
        const floatx4 cgg = __builtin_amdgcn_mfma_f32_16x16x32_bf16(agg.s, band, z, 0, 0, 0); \
        const floatx4 cpg = __builtin_amdgcn_mfma_f32_16x16x32_bf16(apg.s, band, z, 0, 0, 0); \
        const int wb = n * CS + ((t) & 1) * 16 + quad * 4;                   \
        ht_store(&ht[0 * CH_STRIDE + wb], cp);                               \
        ht_store(&ht[1 * CH_STRIDE + wb], cg);                               \
        ht_store(&ht[2 * CH_STRIDE + wb], cpp);                              \
        ht_store(&ht[3 * CH_STRIDE + wb], cgg);                              \
        ht_store(&ht[4 * CH_STRIDE + wb], cpg);                              \
    }

// V window w: lower 16 k-rows from ring slot SLO, upper from slot SHI
#define VPASS(SLO, SHI)                                                      \
    {                                                                        \
        const int koff = ((quad < 2) ? (SLO) : (SHI)) * 16 + (quad & 1) * 8; \
        const int rb   = n * CS + koff;                                      \
        const short8 bp  = ht_load(&ht[0 * CH_STRIDE + rb]);                 \
        const short8 bg  = ht_load(&ht[1 * CH_STRIDE + rb]);                 \
        const short8 bpp = ht_load(&ht[2 * CH_STRIDE + rb]);                 \
        const short8 bgg = ht_load(&ht[3 * CH_STRIDE + rb]);                 \
        const short8 bpg = ht_load(&ht[4 * CH_STRIDE + rb]);                 \
        const floatx4 z = {0.f, 0.f, 0.f, 0.f};                              \
        const floatx4 mp  = __builtin_amdgcn_mfma_f32_16x16x32_bf16(band, bp,  z, 0, 0, 0); \
        const floatx4 mg  = __builtin_amdgcn_mfma_f32_16x16x32_bf16(band, bg,  z, 0, 0, 0); \
        const floatx4 mpp = __builtin_amdgcn_mfma_f32_16x16x32_bf16(band, bpp, z, 0, 0, 0); \
        const floatx4 mgg = __builtin_amdgcn_mfma_f32_16x16x32_bf16(band, bgg, z, 0, 0, 0); \
        const floatx4 mpg = __builtin_amdgcn_mfma_f32_16x16x32_bf16(band, bpg, z, 0, 0, 0); \
        _Pragma("unroll")                                                    \
        for (int r = 0; r < 4; ++r) {                                        \
            const float mu1 = mp[r], mu2 = mg[r];                            \
            const float mu1sq = mu1 * mu1, mu2sq = mu2 * mu2;                \
            const float mu12 = mu1 * mu2;                                    \
            const float s1  = mpp[r] - mu1sq;                                \
            const float s2  = mgg[r] - mu2sq;                                \
            const float s12 = mpg[r] - mu12;                                 \
            const float num = (2.f * mu12 + C1) * (2.f * s12 + C2);          \
            const float den = (mu1sq + mu2sq + C1) * (s1 + s2 + C2);         \
            lsum += num * __builtin_amdgcn_rcpf(den);                        \
        }                                                                    \
    }

    const float C1 = 1e-4f, C2 = 9e-4f;
    float lsum = 0.f;

    // named buffers, constant indices only -> stays in VGPRs
    float pA[8], gA[8], pB[8], gB[8], pC[8], gC[8];

    LOADT(0, pA, gA)
    LOADT(1, pB, gB)
    LOADT(2, pC, gC)
    COMPT(0, pA, gA)          // slot 0
    LOADT(3, pA, gA)
    COMPT(1, pB, gB)          // slot 1
    VPASS(0, 1)               // window 0: tiles 0,1
    LOADT(4, pB, gB)
    COMPT(2, pC, gC)          // slot 0
    VPASS(1, 0)               // window 1: tiles 1,2
    COMPT(3, pA, gA)          // slot 1
    VPASS(0, 1)               // window 2: tiles 2,3
    COMPT(4, pB, gB)          // slot 0
    VPASS(1, 0)               // window 3: tiles 3,4

    // ---- block reduction -> one partial per block ----
#pragma unroll
    for (int off = 32; off > 0; off >>= 1)
        lsum += __shfl_down(lsum, off);
    if (lane == 0) wsum[wv] = lsum;
    __syncthreads();
    if (tid == 0)
        partials[(plane * 8 + by) * 8 + bx] =
            wsum[0] + wsum[1] + wsum[2] + wsum[3];
}

__global__ __launch_bounds__(1024) void ssim_finalize(
        const float* __restrict__ partials, float* __restrict__ out,
        int nparts, double inv_n)
{
    __shared__ double ws[16];
    double s = 0.0;
    for (int i = threadIdx.x; i < nparts; i += 1024)
        s += (double)partials[i];
#pragma unroll
    for (int off = 32; off > 0; off >>= 1)
        s += __shfl_down(s, off);
    if ((threadIdx.x & 63) == 0) ws[threadIdx.x >> 6] = s;
    __syncthreads();
    if (threadIdx.x == 0) {
        double t = 0.0;
#pragma unroll
        for (int i = 0; i < 16; ++i) t += ws[i];
        out[0] = (float)(1.0 - t * inv_n);
    }
}

extern "C" void kernel_launch(void* const* d_in, const int* in_sizes, int n_in,
                              void* d_out, int out_size, void* d_ws, size_t ws_size,
                              hipStream_t stream)
{
    const float* pred = (const float*)d_in[0];
    const float* gt   = (const float*)d_in[1];
    float* out        = (float*)d_out;
    float* partials   = (float*)d_ws;          // 8*8*48 = 3072 floats

    const long n = (long)in_sizes[0];
    const int planes = (int)(n / (long)(IMG * IMG));   // B*C = 48

    dim3 grid(8, 8, planes);                   // 64-col x 64-row strips
    ssim_mfma_ring2<<<grid, 256, 0, stream>>>(pred, gt, partials);
    ssim_finalize<<<1, 1024, 0, stream>>>(partials, out,
                                          8 * 8 * planes, 1.0 / (double)n);
}

// Round 3
// 160.928 us; speedup vs baseline: 1.2071x; 1.0003x over previous
//
#include <hip/hip_runtime.h>

#define IMG 512
#define CS 36                     // shorts per Ht column: 2 ring slots (32) + 4 pad
#define CH_STRIDE (16 * CS)       // 576 shorts: one channel (16 cols) of one wave
#define WV_STRIDE (5 * CH_STRIDE) // 2880 shorts: one wave's 5 channels
#define SW 84                     // f32 staging row width: 80 data + 4 pad (bank-even, 336B row, 16B-mult)

typedef short short8  __attribute__((ext_vector_type(8)));
typedef float floatx4 __attribute__((ext_vector_type(4)));
typedef int   intx2   __attribute__((ext_vector_type(2)));

// 1D Gaussian (sigma=1.5, K=11) — identical values to prior rounds.
__device__ static constexpr float W11F[11] = {
    0.00102838f, 0.00759876f, 0.03600077f, 0.10936069f, 0.21300554f,
    0.26601173f,
    0.21300554f, 0.10936069f, 0.03600077f, 0.00759876f, 0.00102838f};

// pack two fp32 -> two bf16 (round-half-up; finite positive values)
__device__ __forceinline__ unsigned pack2bf16(float a, float b) {
    const unsigned ua = __float_as_uint(a) + 0x8000u;
    const unsigned ub = __float_as_uint(b) + 0x8000u;
    return __builtin_amdgcn_perm(ub, ua, 0x07060302u);
}

__device__ __forceinline__ void ht_store(ushort* p, floatx4 c) {
    intx2 d;
    d.x = (int)pack2bf16(c[0], c[1]);
    d.y = (int)pack2bf16(c[2], c[3]);
    *(intx2*)p = d;               // 8-B aligned by construction
}

__device__ __forceinline__ short8 ht_load(const ushort* p) {
    union { intx2 d[2]; short8 s; } u;
    u.d[0] = *(const intx2*)p;
    u.d[1] = *(const intx2*)(p + 4);
    return u.s;
}

// Block = 4 waves (256 thr), 64 out-cols. Wave = 16 out-cols x 64 out-rows.
// INTERIOR blocks (bx,by in [1,6]): block-cooperative f32 staging of each
// 16-row x 84-col input tile (pred+gt) via global_load_lds (coalesced,
// double-buffered); H-pass A-fragments come from LDS via ds_read_b128.
// This replaces the 16-row-scattered register loads (32 cache lines per
// VMEM instr) that capped per-CU bandwidth at ~6 GB/s.
// EDGE blocks: proven register-staged path (rounds 0-2), unchanged.
__global__ __launch_bounds__(256, 4) void ssim_mfma_ring2(
        const float* __restrict__ pred, const float* __restrict__ gt,
        float* __restrict__ partials)
{
    __shared__ ushort Ht[4 * WV_STRIDE];     // 23,040 B
    __shared__ float  Sst[2][2][16][SW];     // [buf][arr][row][col] 21,504 B
    __shared__ ushort wlut[16];
    __shared__ float  wsum[4];

    const int tid  = threadIdx.x;
    const int wv   = tid >> 6;
    const int lane = tid & 63;
    const int n    = lane & 15;
    const int quad = lane >> 4;

    if (tid < 16) {
        const float w = (tid < 11) ? W11F[tid] : 0.f;
        wlut[tid] = (ushort)((__float_as_uint(w) + 0x8000u) >> 16);
    }
    __syncthreads();

    // band fragment: w[(quad*8+j) - n - 3]; B in H-pass, A in V-pass.
    short8 band;
#pragma unroll
    for (int j = 0; j < 8; ++j) {
        const int t = quad * 8 + j - n - 3;
        band[j] = (short)wlut[((unsigned)t < 11u) ? t : 15];
    }

    const int bx = blockIdx.x, by = blockIdx.y, plane = blockIdx.z;
    const long pb = (long)plane * (IMG * IMG);
    const float* pplane = pred + pb;
    const float* gplane = gt + pb;
    const int xs  = bx * 64 + wv * 16 - 8;  // 32-col input window start
    const int y0  = by * 64;                // 64-row output strip
    ushort* ht    = &Ht[wv * WV_STRIDE];
    const bool cols_ok = (xs >= 0) && (xs + 32 <= IMG);

// stage tile t (16 input rows starting at y0-8+16t) into named buffers
#define LOADT(t, pf, gf)                                                     \
    {                                                                        \
        const int ys  = y0 - 8 + (t) * 16;                                   \
        const int row = ys + n;                                              \
        const int c0  = xs + quad * 8;                                       \
        if (cols_ok && ys >= 0 && ys + 16 <= IMG) {                          \
            const float* pr = pplane + (long)row * IMG + c0;                 \
            const float* gr = gplane + (long)row * IMG + c0;                 \
            *(float4*)&pf[0] = *(const float4*)pr;                           \
            *(float4*)&pf[4] = *(const float4*)(pr + 4);                     \
            *(float4*)&gf[0] = *(const float4*)gr;                           \
            *(float4*)&gf[4] = *(const float4*)(gr + 4);                     \
        } else {                                                             \
            const bool rv = (unsigned)row < (unsigned)IMG;                   \
            const int rowc = rv ? row : 0;                                   \
            const float* pr = pplane + (long)rowc * IMG;                     \
            const float* gr = gplane + (long)rowc * IMG;                     \
            _Pragma("unroll")                                                \
            for (int j = 0; j < 8; ++j) {                                    \
                const int cc = c0 + j;                                       \
                const bool ok = rv && ((unsigned)cc < (unsigned)IMG);        \
                const int ccc = ok ? cc : 0;                                 \
                const float pv = pr[ccc], gv = gr[ccc];                      \
                pf[j] = ok ? pv : 0.f;                                       \
                gf[j] = ok ? gv : 0.f;                                       \
            }                                                                \
        }                                                                    \
    }

// H-conv tile t via 5 MFMAs, store into ring slot t&1 (k = slot*16 + m)
#define COMPT(t, pf, gf)                                                     \
    {                                                                        \
        union { unsigned u[4]; short8 s; } ap, ag, app, agg, apg;            \
        _Pragma("unroll")                                                    \
        for (int h = 0; h < 4; ++h) {                                        \
            const float p0 = pf[2*h], p1 = pf[2*h+1];                        \
            const float g0 = gf[2*h], g1 = gf[2*h+1];                        \
            ap.u [h] = pack2bf16(p0, p1);                                    \
            ag.u [h] = pack2bf16(g0, g1);                                    \
            app.u[h] = pack2bf16(p0 * p0, p1 * p1);                          \
            agg.u[h] = pack2bf16(g0 * g0, g1 * g1);                          \
            apg.u[h] = pack2bf16(p0 * g0, p1 * g1);                          \
        }                                                                    \
        const floatx4 z = {0.f, 0.f, 0.f, 0.f};                              \
        const floatx4 cp  = __builtin_amdgcn_mfma_f32_16x16x32_bf16(ap.s,  band, z, 0, 0, 0); \
        const floatx4 cg  = __builtin_amdgcn_mfma_f32_16x16x32_bf16(ag.s,  band, z, 0, 0, 0); \
        const floatx4 cpp = __builtin_amdgcn_mfma_f32_16x16x32_bf16(app.s, band, z, 0, 0, 0); \
        const floatx4 cgg = __builtin_amdgcn_mfma_f32_16x16x32_bf16(agg.s, band, z, 0, 0, 0); \
        const floatx4 cpg = __builtin_amdgcn_mfma_f32_16x16x32_bf16(apg.s, band, z, 0, 0, 0); \
        const int wb = n * CS + ((t) & 1) * 16 + quad * 4;                   \
        ht_store(&ht[0 * CH_STRIDE + wb], cp);                               \
        ht_store(&ht[1 * CH_STRIDE + wb], cg);                               \
        ht_store(&ht[2 * CH_STRIDE + wb], cpp);                              \
        ht_store(&ht[3 * CH_STRIDE + wb], cgg);                              \
        ht_store(&ht[4 * CH_STRIDE + wb], cpg);                              \
    }

// V window w: lower 16 k-rows from ring slot SLO, upper from slot SHI
#define VPASS(SLO, SHI)                                                      \
    {                                                                        \
        const int koff = ((quad < 2) ? (SLO) : (SHI)) * 16 + (quad & 1) * 8; \
        const int rb   = n * CS + koff;                                      \
        const short8 bp  = ht_load(&ht[0 * CH_STRIDE + rb]);                 \
        const short8 bg  = ht_load(&ht[1 * CH_STRIDE + rb]);                 \
        const short8 bpp = ht_load(&ht[2 * CH_STRIDE + rb]);                 \
        const short8 bgg = ht_load(&ht[3 * CH_STRIDE + rb]);                 \
        const short8 bpg = ht_load(&ht[4 * CH_STRIDE + rb]);                 \
        const floatx4 z = {0.f, 0.f, 0.f, 0.f};                              \
        const floatx4 mp  = __builtin_amdgcn_mfma_f32_16x16x32_bf16(band, bp,  z, 0, 0, 0); \
        const floatx4 mg  = __builtin_amdgcn_mfma_f32_16x16x32_bf16(band, bg,  z, 0, 0, 0); \
        const floatx4 mpp = __builtin_amdgcn_mfma_f32_16x16x32_bf16(band, bpp, z, 0, 0, 0); \
        const floatx4 mgg = __builtin_amdgcn_mfma_f32_16x16x32_bf16(band, bgg, z, 0, 0, 0); \
        const floatx4 mpg = __builtin_amdgcn_mfma_f32_16x16x32_bf16(band, bpg, z, 0, 0, 0); \
        _Pragma("unroll")                                                    \
        for (int r = 0; r < 4; ++r) {                                        \
            const float mu1 = mp[r], mu2 = mg[r];                            \
            const float mu1sq = mu1 * mu1, mu2sq = mu2 * mu2;                \
            const float mu12 = mu1 * mu2;                                    \
            const float s1  = mpp[r] - mu1sq;                                \
            const float s2  = mgg[r] - mu2sq;                                \
            const float s12 = mpg[r] - mu12;                                 \
            const float num = (2.f * mu12 + C1) * (2.f * s12 + C2);          \
            const float den = (mu1sq + mu2sq + C1) * (s1 + s2 + C2);         \
            lsum += num * __builtin_amdgcn_rcpf(den);                        \
        }                                                                    \
    }

// stage tile t of both arrays into Sst[b] via global_load_lds.
// Wave wv stages its 4-row slab (rows wv*4..wv*4+3, 84 f32/row = 336 floats):
// instr1: 64 lanes x 16B = floats 0..255 of slab; instr2: lanes<20 cover
// floats 256..335. LDS dest = wave-uniform base + lane*16B (HW rule).
#define STG(t, b)                                                            \
    {                                                                        \
        const long gb = (long)(y0 - 8 + (t) * 16) * IMG;                     \
        const float* g1p = pplane + gb + so1;                                \
        const float* g1g = gplane + gb + so1;                                \
        float* d_p = &Sst[b][0][wv * 4][0];                                  \
        float* d_g = &Sst[b][1][wv * 4][0];                                  \
        __builtin_amdgcn_global_load_lds(                                    \
            (const __attribute__((address_space(1))) void*)g1p,              \
            (__attribute__((address_space(3))) void*)d_p, 16, 0, 0);         \
        __builtin_amdgcn_global_load_lds(                                    \
            (const __attribute__((address_space(1))) void*)g1g,              \
            (__attribute__((address_space(3))) void*)d_g, 16, 0, 0);         \
        if (lane < 20) {                                                     \
            const float* g2p = pplane + gb + so2;                            \
            const float* g2g = gplane + gb + so2;                            \
            __builtin_amdgcn_global_load_lds(                                \
                (const __attribute__((address_space(1))) void*)g2p,          \
                (__attribute__((address_space(3))) void*)(d_p + 256), 16, 0, 0); \
            __builtin_amdgcn_global_load_lds(                                \
                (const __attribute__((address_space(1))) void*)g2g,          \
                (__attribute__((address_space(3))) void*)(d_g + 256), 16, 0, 0); \
        }                                                                    \
    }

// H-pass sourcing A-fragments from staged LDS tile: lane(n,quad) reads
// row n, cols wv*16+quad*8 .. +7 (two aligned ds_read_b128 per array).
#define COMPF(t, b)                                                          \
    {                                                                        \
        const float* sp_ = &Sst[b][0][n][wv * 16 + quad * 8];                \
        const float* sg_ = &Sst[b][1][n][wv * 16 + quad * 8];                \
        float pf[8], gf[8];                                                  \
        *(float4*)&pf[0] = *(const float4*)sp_;                              \
        *(float4*)&pf[4] = *(const float4*)(sp_ + 4);                        \
        *(float4*)&gf[0] = *(const float4*)sg_;                              \
        *(float4*)&gf[4] = *(const float4*)(sg_ + 4);                        \
        COMPT(t, pf, gf)                                                     \
    }

    const float C1 = 1e-4f, C2 = 9e-4f;
    float lsum = 0.f;

    const bool interior = (bx >= 1) && (bx <= 6) && (by >= 1) && (by <= 6);

    if (interior) {
        // ---- fast path: coalesced global_load_lds staging, dbuf ----
        const int  xc = bx * 64 - 8;                 // block input col start
        const int  r1 = lane / 21;                   // slab-relative row, instr1
        const int  c1 = (lane % 21) * 4;             // col (floats), instr1
        const long so1 = (long)(wv * 4 + r1) * IMG + xc + c1;
        const long so2 = (long)(wv * 4 + 3)  * IMG + xc + (lane + 1) * 4;

        STG(0, 0)
        __syncthreads();                 // buf0 staged (syncthreads drains vmcnt)
        STG(1, 1)
        COMPF(0, 0)                      // ring slot 0
        __syncthreads();                 // buf1 staged; buf0 free
        STG(2, 0)
        COMPF(1, 1)                      // slot 1
        VPASS(0, 1)                      // window 0: tiles 0,1
        __syncthreads();
        STG(3, 1)
        COMPF(2, 0)                      // slot 0
        VPASS(1, 0)                      // window 1: tiles 1,2
        __syncthreads();
        STG(4, 0)
        COMPF(3, 1)                      // slot 1
        VPASS(0, 1)                      // window 2: tiles 2,3
        __syncthreads();
        COMPF(4, 0)                      // slot 0
        VPASS(1, 0)                      // window 3: tiles 3,4
    } else {
        // ---- edge path: register staging (rounds 0-2, proven) ----
        float pA[8], gA[8], pB[8], gB[8], pC[8], gC[8];

        LOADT(0, pA, gA)
        LOADT(1, pB, gB)
        LOADT(2, pC, gC)
        COMPT(0, pA, gA)          // slot 0
        LOADT(3, pA, gA)
        COMPT(1, pB, gB)          // slot 1
        VPASS(0, 1)               // window 0: tiles 0,1
        LOADT(4, pB, gB)
        COMPT(2, pC, gC)          // slot 0
        VPASS(1, 0)               // window 1: tiles 1,2
        COMPT(3, pA, gA)          // slot 1
        VPASS(0, 1)               // window 2: tiles 2,3
        COMPT(4, pB, gB)          // slot 0
        VPASS(1, 0)               // window 3: tiles 3,4
    }

    // ---- block reduction -> one partial per block ----
#pragma unroll
    for (int off = 32; off > 0; off >>= 1)
        lsum += __shfl_down(lsum, off);
    if (lane == 0) wsum[wv] = lsum;
    __syncthreads();
    if (tid == 0)
        partials[(plane * 8 + by) * 8 + bx] =
            wsum[0] + wsum[1] + wsum[2] + wsum[3];
}

__global__ __launch_bounds__(1024) void ssim_finalize(
        const float* __restrict__ partials, float* __restrict__ out,
        int nparts, double inv_n)
{
    __shared__ double ws[16];
    double s = 0.0;
    for (int i = threadIdx.x; i < nparts; i += 1024)
        s += (double)partials[i];
#pragma unroll
    for (int off = 32; off > 0; off >>= 1)
        s += __shfl_down(s, off);
    if ((threadIdx.x & 63) == 0) ws[threadIdx.x >> 6] = s;
    __syncthreads();
    if (threadIdx.x == 0) {
        double t = 0.0;
#pragma unroll
        for (int i = 0; i < 16; ++i) t += ws[i];
        out[0] = (float)(1.0 - t * inv_n);
    }
}

extern "C" void kernel_launch(void* const* d_in, const int* in_sizes, int n_in,
                              void* d_out, int out_size, void* d_ws, size_t ws_size,
                              hipStream_t stream)
{
    const float* pred = (const float*)d_in[0];
    const float* gt   = (const float*)d_in[1];
    float* out        = (float*)d_out;
    float* partials   = (float*)d_ws;          // 8*8*48 = 3072 floats

    const long n = (long)in_sizes[0];
    const int planes = (int)(n / (long)(IMG * IMG));   // B*C = 48

    dim3 grid(8, 8, planes);                   // 64-col x 64-row strips
    ssim_mfma_ring2<<<grid, 256, 0, stream>>>(pred, gt, partials);
    ssim_finalize<<<1, 1024, 0, stream>>>(partials, out,
                                          8 * 8 * planes, 1.0 / (double)n);
}